// Round 1
// baseline (11635.406 us; speedup 1.0000x reference)
//
#include <hip/hip_runtime.h>

// GRU encoder-decoder, persistent-wave fp32 design.
// B=8192, H=64, 512 enc + 180 dec steps. 1024 blocks x 64 threads:
// each single-wave block owns 8 batch elements for the whole sequence.
// Lane j owns gate rows {j, 64+j, 128+j} -> gating is lane-local.
// h0/h1 in LDS [k][8+pad]; GEMM reads are wave-uniform (LDS broadcast).
// Weights pre-transposed to ws as [k][j][3] -> 12B dwordx3 per lane per k,
// coalesced 768B per wave, L2-resident, prefetched one k-block ahead.

#define HSTR 12   // 8 batch + 4 pad floats: keeps float4 rows 16B-aligned

struct Params {
  const float *x;
  const float *wih0e, *bih0e, *bhh0e, *bih1e, *bhh1e;
  const float *wih0d, *bih0d, *bhh0d, *bih1d, *bhh1d;
  const float *outW, *outb;
  const float *wt;   // [6][64][64][3] transposed weights in d_ws
  float *out;
};

__device__ __forceinline__ float sgm(float v) { return 1.f / (1.f + __expf(-v)); }
__device__ __forceinline__ float th(float v)  { float e = __expf(2.f * v); return 1.f - 2.f / (e + 1.f); }

// Transpose the six 192x64 matrices into [k][j][g] packing (g = gate block 0..2,
// row = g*64+j, col = k). dst[i], i = k*192 + j*3 + g  <-  src[(g*64+j)*64 + k].
__global__ void prep_w(const float* s0, const float* s1, const float* s2,
                       const float* s3, const float* s4, const float* s5, float* dst) {
  const float* srcs[6] = {s0, s1, s2, s3, s4, s5};
  const float* s = srcs[blockIdx.x];
  float* o = dst + blockIdx.x * 12288;
  for (int i = threadIdx.x; i < 12288; i += blockDim.x) {
    int g = i % 3, jj = (i / 3) % 64, k = i / 192;
    o[i] = s[(g * 64 + jj) * 64 + k];
  }
}

// Single GEMM: ah[b][g] += sum_k hs[k][b] * wt[k][j][g]   (k=64)
__device__ __forceinline__ void gemm1(const float* wt, const float* hs, int j,
                                      float ah[8][3]) {
  float3 wA[8];
#pragma unroll
  for (int u = 0; u < 8; ++u) wA[u] = *(const float3*)(wt + (u * 64 + j) * 3);
  for (int kb = 0; kb < 64; kb += 8) {
    int kn = (kb + 8) & 63;             // wraps to 0 on last block (harmless reload)
    float3 wB[8];
#pragma unroll
    for (int u = 0; u < 8; ++u) wB[u] = *(const float3*)(wt + ((kn + u) * 64 + j) * 3);
#pragma unroll
    for (int u = 0; u < 8; ++u) {
      int k = kb + u;
      float4 a0 = *(const float4*)&hs[k * HSTR];
      float4 a1 = *(const float4*)&hs[k * HSTR + 4];
      float hv[8] = {a0.x, a0.y, a0.z, a0.w, a1.x, a1.y, a1.z, a1.w};
#pragma unroll
      for (int b = 0; b < 8; ++b) {
        ah[b][0] += hv[b] * wA[u].x;
        ah[b][1] += hv[b] * wA[u].y;
        ah[b][2] += hv[b] * wA[u].z;
      }
    }
#pragma unroll
    for (int u = 0; u < 8; ++u) wA[u] = wB[u];
  }
}

// Dual GEMM: ai += Wih^T-slice @ xs,  ah += Whh^T-slice @ hs
__device__ __forceinline__ void gemm2(const float* wi_, const float* wh_,
                                      const float* xs, const float* hs, int j,
                                      float ai[8][3], float ah[8][3]) {
  float3 wiA[4], whA[4];
#pragma unroll
  for (int u = 0; u < 4; ++u) {
    wiA[u] = *(const float3*)(wi_ + (u * 64 + j) * 3);
    whA[u] = *(const float3*)(wh_ + (u * 64 + j) * 3);
  }
  for (int kb = 0; kb < 64; kb += 4) {
    int kn = (kb + 4) & 63;
    float3 wiB[4], whB[4];
#pragma unroll
    for (int u = 0; u < 4; ++u) {
      wiB[u] = *(const float3*)(wi_ + ((kn + u) * 64 + j) * 3);
      whB[u] = *(const float3*)(wh_ + ((kn + u) * 64 + j) * 3);
    }
#pragma unroll
    for (int u = 0; u < 4; ++u) {
      int k = kb + u;
      float4 a0 = *(const float4*)&xs[k * HSTR];
      float4 a1 = *(const float4*)&xs[k * HSTR + 4];
      float4 c0 = *(const float4*)&hs[k * HSTR];
      float4 c1 = *(const float4*)&hs[k * HSTR + 4];
      float xv[8] = {a0.x, a0.y, a0.z, a0.w, a1.x, a1.y, a1.z, a1.w};
      float hv[8] = {c0.x, c0.y, c0.z, c0.w, c1.x, c1.y, c1.z, c1.w};
#pragma unroll
      for (int b = 0; b < 8; ++b) {
        ai[b][0] += xv[b] * wiA[u].x;
        ai[b][1] += xv[b] * wiA[u].y;
        ai[b][2] += xv[b] * wiA[u].z;
        ah[b][0] += hv[b] * whA[u].x;
        ah[b][1] += hv[b] * whA[u].y;
        ah[b][2] += hv[b] * whA[u].z;
      }
    }
#pragma unroll
    for (int u = 0; u < 4; ++u) { wiA[u] = wiB[u]; whA[u] = whB[u]; }
  }
}

__global__ __launch_bounds__(64) void gru_main(Params p) {
  __shared__ __align__(16) float h0s[64 * HSTR];
  __shared__ __align__(16) float h1s[64 * HSTR];
  const int j = threadIdx.x;          // lane = gate index j (rows j, 64+j, 128+j)
  const int b0 = blockIdx.x * 8;      // batch base

  // ---- preload per-lane biases / tiny input weights ----
  float bi0e[3], bh0e[3], bi1e[3], bh1e[3], wx0[3][2];
  float bi0d[3], bh0d[3], bi1d[3], bh1d[3], wd0[3];
#pragma unroll
  for (int g = 0; g < 3; ++g) {
    int r = g * 64 + j;
    bi0e[g] = p.bih0e[r]; bh0e[g] = p.bhh0e[r];
    bi1e[g] = p.bih1e[r]; bh1e[g] = p.bhh1e[r];
    wx0[g][0] = p.wih0e[2 * r]; wx0[g][1] = p.wih0e[2 * r + 1];
    bi0d[g] = p.bih0d[r]; bh0d[g] = p.bhh0d[r];
    bi1d[g] = p.bih1d[r]; bh1d[g] = p.bhh1d[r];
    wd0[g] = p.wih0d[r];
  }
  const float oW = p.outW[j], ob = p.outb[0];

  const float* wE0  = p.wt;
  const float* wE1i = p.wt + 12288;
  const float* wE1h = p.wt + 24576;
  const float* wD0  = p.wt + 36864;
  const float* wD1i = p.wt + 49152;
  const float* wD1h = p.wt + 61440;

  float h0own[8], h1own[8];
#pragma unroll
  for (int b = 0; b < 8; ++b) { h0own[b] = 0.f; h1own[b] = 0.f; }
  *(float4*)&h0s[j * HSTR]     = make_float4(0, 0, 0, 0);
  *(float4*)&h0s[j * HSTR + 4] = make_float4(0, 0, 0, 0);
  *(float4*)&h1s[j * HSTR]     = make_float4(0, 0, 0, 0);
  *(float4*)&h1s[j * HSTR + 4] = make_float4(0, 0, 0, 0);

  // =================== encoder: 512 steps ===================
  for (int t = 0; t < 512; ++t) {
    float xv0[8], xv1[8];
#pragma unroll
    for (int b = 0; b < 8; ++b) {  // wave-uniform 8B loads, L1-broadcast
      float2 xx = *(const float2*)(p.x + ((size_t)(b0 + b) * 512 + t) * 2);
      xv0[b] = xx.x; xv1[b] = xx.y;
    }
    // ---- cell0: gh = Whh0 @ h0 ----
    float ah[8][3];
#pragma unroll
    for (int b = 0; b < 8; ++b) { ah[b][0] = 0.f; ah[b][1] = 0.f; ah[b][2] = 0.f; }
    gemm1(wE0, h0s, j, ah);
#pragma unroll
    for (int b = 0; b < 8; ++b) {
      float ir  = bi0e[0] + wx0[0][0] * xv0[b] + wx0[0][1] * xv1[b];
      float iz  = bi0e[1] + wx0[1][0] * xv0[b] + wx0[1][1] * xv1[b];
      float inn = bi0e[2] + wx0[2][0] * xv0[b] + wx0[2][1] * xv1[b];
      float r = sgm(ir + bh0e[0] + ah[b][0]);
      float z = sgm(iz + bh0e[1] + ah[b][1]);
      float n = th(inn + r * (bh0e[2] + ah[b][2]));
      h0own[b] = (1.f - z) * n + z * h0own[b];
    }
    // publish h0 (wave-lockstep: all GEMM reads above already done)
    *(float4*)&h0s[j * HSTR]     = make_float4(h0own[0], h0own[1], h0own[2], h0own[3]);
    *(float4*)&h0s[j * HSTR + 4] = make_float4(h0own[4], h0own[5], h0own[6], h0own[7]);

    // ---- cell1: gi = Wih1 @ h0new, gh = Whh1 @ h1 ----
    float ai[8][3], ah1[8][3];
#pragma unroll
    for (int b = 0; b < 8; ++b) {
      ai[b][0] = 0.f; ai[b][1] = 0.f; ai[b][2] = 0.f;
      ah1[b][0] = 0.f; ah1[b][1] = 0.f; ah1[b][2] = 0.f;
    }
    gemm2(wE1i, wE1h, h0s, h1s, j, ai, ah1);
#pragma unroll
    for (int b = 0; b < 8; ++b) {
      float r = sgm(ai[b][0] + bi1e[0] + bh1e[0] + ah1[b][0]);
      float z = sgm(ai[b][1] + bi1e[1] + bh1e[1] + ah1[b][1]);
      float n = th(ai[b][2] + bi1e[2] + r * (bh1e[2] + ah1[b][2]));
      h1own[b] = (1.f - z) * n + z * h1own[b];
    }
    *(float4*)&h1s[j * HSTR]     = make_float4(h1own[0], h1own[1], h1own[2], h1own[3]);
    *(float4*)&h1s[j * HSTR + 4] = make_float4(h1own[4], h1own[5], h1own[6], h1own[7]);
  }

  // =================== decoder: 180 steps ===================
  float prev[8];
#pragma unroll
  for (int b = 0; b < 8; ++b) prev[b] = 0.f;

  for (int t = 0; t < 180; ++t) {
    // ---- cell0: input = prev (scalar per batch) ----
    float ah[8][3];
#pragma unroll
    for (int b = 0; b < 8; ++b) { ah[b][0] = 0.f; ah[b][1] = 0.f; ah[b][2] = 0.f; }
    gemm1(wD0, h0s, j, ah);
#pragma unroll
    for (int b = 0; b < 8; ++b) {
      float r = sgm(bi0d[0] + wd0[0] * prev[b] + bh0d[0] + ah[b][0]);
      float z = sgm(bi0d[1] + wd0[1] * prev[b] + bh0d[1] + ah[b][1]);
      float n = th(bi0d[2] + wd0[2] * prev[b] + r * (bh0d[2] + ah[b][2]));
      h0own[b] = (1.f - z) * n + z * h0own[b];
    }
    *(float4*)&h0s[j * HSTR]     = make_float4(h0own[0], h0own[1], h0own[2], h0own[3]);
    *(float4*)&h0s[j * HSTR + 4] = make_float4(h0own[4], h0own[5], h0own[6], h0own[7]);

    // ---- cell1 ----
    float ai[8][3], ah1[8][3];
#pragma unroll
    for (int b = 0; b < 8; ++b) {
      ai[b][0] = 0.f; ai[b][1] = 0.f; ai[b][2] = 0.f;
      ah1[b][0] = 0.f; ah1[b][1] = 0.f; ah1[b][2] = 0.f;
    }
    gemm2(wD1i, wD1h, h0s, h1s, j, ai, ah1);
#pragma unroll
    for (int b = 0; b < 8; ++b) {
      float r = sgm(ai[b][0] + bi1d[0] + bh1d[0] + ah1[b][0]);
      float z = sgm(ai[b][1] + bi1d[1] + bh1d[1] + ah1[b][1]);
      float n = th(ai[b][2] + bi1d[2] + r * (bh1d[2] + ah1[b][2]));
      h1own[b] = (1.f - z) * n + z * h1own[b];
    }
    *(float4*)&h1s[j * HSTR]     = make_float4(h1own[0], h1own[1], h1own[2], h1own[3]);
    *(float4*)&h1s[j * HSTR + 4] = make_float4(h1own[4], h1own[5], h1own[6], h1own[7]);

    // ---- output: cv[b] = sum_j outW[j]*h1[b][j] + ob; butterfly over 64 lanes ----
    float v[8];
#pragma unroll
    for (int b = 0; b < 8; ++b) v[b] = oW * h1own[b];
#pragma unroll
    for (int off = 32; off >= 1; off >>= 1) {
#pragma unroll
      for (int b = 0; b < 8; ++b) v[b] += __shfl_xor(v[b], off, 64);
    }
    float ov = v[0] + ob;
#pragma unroll
    for (int b = 1; b < 8; ++b) ov = (j == b) ? (v[b] + ob) : ov;
    if (j < 8) p.out[(size_t)(b0 + j) * 180 + t] = ov;
#pragma unroll
    for (int b = 0; b < 8; ++b) prev[b] = v[b] + ob;  // autoregressive feedback
  }
}

extern "C" void kernel_launch(void* const* d_in, const int* in_sizes, int n_in,
                              void* d_out, int out_size, void* d_ws, size_t ws_size,
                              hipStream_t stream) {
  // input order: 0 x, 1 enc_Wih0, 2 enc_Whh0, 3 enc_bih0, 4 enc_bhh0,
  // 5 enc_Wih1, 6 enc_Whh1, 7 enc_bih1, 8 enc_bhh1, 9 dec_Wih0, 10 dec_Whh0,
  // 11 dec_bih0, 12 dec_bhh0, 13 dec_Wih1, 14 dec_Whh1, 15 dec_bih1,
  // 16 dec_bhh1, 17 out_W, 18 out_b
  float* wt = (float*)d_ws;  // needs 6*12288*4 = 294912 B of scratch

  prep_w<<<dim3(6), dim3(256), 0, stream>>>(
      (const float*)d_in[2], (const float*)d_in[5], (const float*)d_in[6],
      (const float*)d_in[10], (const float*)d_in[13], (const float*)d_in[14], wt);

  Params p;
  p.x = (const float*)d_in[0];
  p.wih0e = (const float*)d_in[1];
  p.bih0e = (const float*)d_in[3];
  p.bhh0e = (const float*)d_in[4];
  p.bih1e = (const float*)d_in[7];
  p.bhh1e = (const float*)d_in[8];
  p.wih0d = (const float*)d_in[9];
  p.bih0d = (const float*)d_in[11];
  p.bhh0d = (const float*)d_in[12];
  p.bih1d = (const float*)d_in[15];
  p.bhh1d = (const float*)d_in[16];
  p.outW = (const float*)d_in[17];
  p.outb = (const float*)d_in[18];
  p.wt = wt;
  p.out = (float*)d_out;

  gru_main<<<dim3(1024), dim3(64), 0, stream>>>(p);
}